// Round 9
// baseline (951.249 us; speedup 1.0000x reference)
//
#include <hip/hip_runtime.h>
#include <hip/hip_bf16.h>

// ---------------------------------------------------------------------------
// ArrowTransformer forward: B=2, S=1024, D=1024, H=16, HD=64, L=6, V=256
// Round 13 (base = R12/901us):
//  * attn_main: 1024-key chunks -> ONE block per q-tile (16 chunk blocks/bh,
//    heavy-first). Split-K machinery removed entirely: no PO/PM/PL partials,
//    no attn_combine kernel (6 fewer dispatches), direct-write everywhere.
//    Iteration body byte-identical to the proven R11/R12 one.
//  * gemm_lds BK=64, prep_weights 64x128, ln one-wave-per-row: from R12.
// ---------------------------------------------------------------------------

typedef __attribute__((ext_vector_type(8))) short  s8_t;
typedef __attribute__((ext_vector_type(4))) short  s4_t;
typedef __attribute__((ext_vector_type(8))) __bf16 bf8_t;
typedef __attribute__((ext_vector_type(4))) float  f4v;

static __device__ __forceinline__ short f2bf(float f) {
  union { float f; unsigned u; } a; a.f = f;
  unsigned u = a.u;
  u += 0x7fffu + ((u >> 16) & 1u);
  return (short)(u >> 16);
}
static __device__ __forceinline__ float bf2f(short s) {
  union { float f; unsigned u; } a;
  a.u = ((unsigned)(unsigned short)s) << 16;
  return a.f;
}
static __device__ __forceinline__ f4v mfma16(s8_t a, s8_t b, f4v c) {
  return __builtin_amdgcn_mfma_f32_16x16x32_bf16(
      __builtin_bit_cast(bf8_t, a), __builtin_bit_cast(bf8_t, b), c, 0, 0, 0);
}
static __device__ __forceinline__ void gld16(const short* g, short* l) {
  __builtin_amdgcn_global_load_lds(
      (const __attribute__((address_space(1))) void*)g,
      (__attribute__((address_space(3))) void*)l, 16, 0, 0);
}

// ---------------------------------------------------------------------------
// Unified weight prep: all transposes (f32 -> bf16, [N][K] layout).
// 64x128 input tiles, 256 threads, grid 3872.
// ---------------------------------------------------------------------------
__global__ __launch_bounds__(256) void prep_weights(
    const float* __restrict__ Wq, const float* __restrict__ Wk,
    const float* __restrict__ Wv, const float* __restrict__ Wo,
    const float* __restrict__ W1, const float* __restrict__ W2,
    const float* __restrict__ Wf,
    short* __restrict__ qkvT, short* __restrict__ WoT, short* __restrict__ W1T,
    short* __restrict__ W2T, short* __restrict__ WfT) {
  __shared__ float tile[64][133];
  int z = blockIdx.x;
  const float* in; short* out; int R, C; long outBS; int rowOff = 0;
  if (z < 2304) {
    R = 1024; C = 1024; outBS = (long)3072 * 1024; out = qkvT;
    if (z < 768)       { in = Wq; }
    else if (z < 1536) { in = Wk; rowOff = 1024; z -= 768; }
    else               { in = Wv; rowOff = 2048; z -= 1536; }
  } else if (z < 3072) { in = Wo; out = WoT; R = 1024; C = 1024; outBS = (long)1024 * 1024; z -= 2304; }
  else if (z < 3456)   { in = W1; out = W1T; R = 1024; C = 512;  outBS = (long)512 * 1024;  z -= 3072; }
  else if (z < 3840)   { in = W2; out = W2T; R = 512;  C = 1024; outBS = (long)1024 * 512;  z -= 3456; }
  else                 { in = Wf; out = WfT; R = 1024; C = 256;  outBS = 0;                 z -= 3840; }
  const int nx = C >> 7, ny = R >> 6;
  const int per = nx * ny;
  const int l = z / per, rem = z % per;
  const int cx = rem % nx, cy = rem / nx;
  in += (long)l * R * C;
  out += (long)l * outBS + (long)rowOff * R;
  const int c0 = cx * 128, r0 = cy * 64;
  const int tid = threadIdx.x;

  const int lr = tid >> 4, lc4 = tid & 15;
#pragma unroll
  for (int p = 0; p < 4; p++) {
    const int row = p * 16 + lr;
#pragma unroll
    for (int h = 0; h < 2; h++) {
      const float4 v = *(const float4*)(in + (long)(r0 + row) * C + c0 + h * 64 + lc4 * 4);
      tile[row][h * 64 + lc4 * 4 + 0] = v.x;
      tile[row][h * 64 + lc4 * 4 + 1] = v.y;
      tile[row][h * 64 + lc4 * 4 + 2] = v.z;
      tile[row][h * 64 + lc4 * 4 + 3] = v.w;
    }
  }
  __syncthreads();
  const int seg = tid & 7;
#pragma unroll
  for (int q = 0; q < 4; q++) {
    const int oc = q * 32 + (tid >> 3);   // output row = source column (0..127)
    s8_t o;
#pragma unroll
    for (int j = 0; j < 8; j++) o[j] = f2bf(tile[seg * 8 + j][oc]);
    *(s8_t*)(out + (long)(c0 + oc) * R + r0 + seg * 8) = o;
  }
}

// ---------------------------------------------------------------------------
// Misc prep: embed+PE (blocks 0..2047), E->bf16 (2048..2431),
// qkv bias concat (2432..2503), fnp (2504..2505). 256 threads.
// ---------------------------------------------------------------------------
__global__ __launch_bounds__(256) void prep_misc(
    const int* __restrict__ x, const float* __restrict__ emb,
    const float* __restrict__ E,
    const float* __restrict__ bq, const float* __restrict__ bk,
    const float* __restrict__ bv,
    short* __restrict__ h, short* __restrict__ Ebf,
    float* __restrict__ qkvB, int* __restrict__ fnp) {
  const int z = blockIdx.x;
  const int tid = threadIdx.x;
  if (z < 2048) {
    const int s = z & 1023;
    const int xv = x[z];
    const int c = tid << 2;
    const float4 e = *(const float4*)(emb + (long)xv * 1024 + c);
    const float ev[4] = {e.x, e.y, e.z, e.w};
    s4_t o;
#pragma unroll
    for (int i = 0; i < 4; i++) {
      const int d = c + i;
      const float par = (float)(d & 1);
      const float rate = expf(-9.210340371976184f * (float)d / 1024.0f) *
                         expf(9.210340371976184f * par / 1024.0f);
      const float pe = sinf((float)s * rate + 1.5707963267948966f * par);
      o[i] = f2bf(ev[i] * 32.0f + pe);
    }
    *(s4_t*)(h + (long)z * 1024 + c) = o;
  } else if (z < 2432) {
    const long i = ((long)(z - 2048) * 256 + tid) * 4;
    const float4 t = *(const float4*)(E + i);
    s4_t o = {f2bf(t.x), f2bf(t.y), f2bf(t.z), f2bf(t.w)};
    *(s4_t*)(Ebf + i) = o;
  } else if (z < 2504) {
    const int idx = (z - 2432) * 256 + tid;
    const int l = idx / 3072, n = idx % 3072;
    float v = (n < 1024) ? bq[l * 1024 + n]
            : (n < 2048) ? bk[l * 1024 + n - 1024]
                         : bv[l * 1024 + n - 2048];
    qkvB[idx] = v;
  } else {
    if (tid < 64) {
      const int b = z - 2504;
      int first = 1024;
      for (int j0 = 0; j0 < 1024; j0 += 64) {
        unsigned long long m = __ballot(x[b * 1024 + j0 + tid] != 0);
        if (m) { first = j0 + __ffsll(m) - 1; break; }
      }
      if (tid == 0) fnp[b] = first;
    }
  }
}

// ---------------------------------------------------------------------------
// LayerNorm over D=1024, bf16 in/out. ONE WAVE per row (no barriers/LDS).
// grid 512 x 256 threads (4 rows/block). In-place safe.
// ---------------------------------------------------------------------------
__global__ __launch_bounds__(256) void ln_kernel(const short* __restrict__ in,
                                                 short* __restrict__ out,
                                                 const float* __restrict__ g,
                                                 const float* __restrict__ be) {
  const int tid = threadIdx.x;
  const int row = blockIdx.x * 4 + (tid >> 6);
  const int lane = tid & 63;
  const int c = lane * 16;
  const short* ip = in + (long)row * 1024 + c;
  s4_t xv[4];
#pragma unroll
  for (int t = 0; t < 4; t++) xv[t] = *(const s4_t*)(ip + t * 4);
  float xs[16];
  float s = 0.f;
#pragma unroll
  for (int t = 0; t < 4; t++)
#pragma unroll
    for (int i = 0; i < 4; i++) {
      xs[t * 4 + i] = bf2f(xv[t][i]);
      s += xs[t * 4 + i];
    }
#pragma unroll
  for (int off = 1; off < 64; off <<= 1) s += __shfl_xor(s, off);
  const float mu = s * (1.0f / 1024.0f);
  float q = 0.f;
#pragma unroll
  for (int t = 0; t < 16; t++) {
    xs[t] -= mu;
    q += xs[t] * xs[t];
  }
#pragma unroll
  for (int off = 1; off < 64; off <<= 1) q += __shfl_xor(q, off);
  const float var = q * (1.0f / 1024.0f);
  const float rs = rsqrtf(var + 1e-6f);
  short* op = out + (long)row * 1024 + c;
#pragma unroll
  for (int t = 0; t < 4; t++) {
    const float4 gv = *(const float4*)(g + c + t * 4);
    const float4 bv = *(const float4*)(be + c + t * 4);
    s4_t o = {f2bf(xs[t * 4 + 0] * rs * gv.x + bv.x),
              f2bf(xs[t * 4 + 1] * rs * gv.y + bv.y),
              f2bf(xs[t * 4 + 2] * rs * gv.z + bv.z),
              f2bf(xs[t * 4 + 3] * rs * gv.w + bv.w)};
    *(s4_t*)(op + t * 4) = o;
  }
}

// ---------------------------------------------------------------------------
// Generic MFMA GEMM: C[m][n] = sum_k A[m][k]*BT[n][k] (+bias) (+relu)
// BK=64 via two half-tiles per barrier window (proven R12 structure).
// ---------------------------------------------------------------------------
template <int BM, int BN, int WR, int WC, int OUT_BF16, int RELU>
__global__ __launch_bounds__(256) void gemm_lds(
    const short* __restrict__ A, const short* __restrict__ BT,
    void* __restrict__ Cv, const float* __restrict__ biasp,
    int K, int lda, int ldb, int ldc) {
  constexpr int AR = BM / 64, BR = BN / 64;
  constexpr int FI = BM / WR / 16, FJ = BN / WC / 16;
  __shared__ short As[2 * BM * 32];
  __shared__ short Bs[2 * BN * 32];
  const int bm = blockIdx.y * BM, bn = blockIdx.x * BN;
  const int tid = threadIdx.x;
  const int wave = tid >> 6, lane = tid & 63;
  const int quad = lane >> 4, l16 = lane & 15;
  const int wr = wave / WC, wc = wave % WC;
  const int wm = wr * (BM / WR), wn = wc * (BN / WC);

  const short* Ag = A + (long)(bm + wave * 16 + (lane >> 2)) * lda + ((lane & 3) << 3);
  const short* Bg = BT + (long)(bn + wave * 16 + (lane >> 2)) * ldb + ((lane & 3) << 3);

  f4v acc[FI][FJ];
#pragma unroll
  for (int i = 0; i < FI; i++)
#pragma unroll
    for (int j = 0; j < FJ; j++) {
      f4v zz = {0.f, 0.f, 0.f, 0.f};
      acc[i][j] = zz;
    }

  for (int k0 = 0; k0 < K; k0 += 64) {
#pragma unroll
    for (int h = 0; h < 2; h++) {
#pragma unroll
      for (int r = 0; r < AR; r++)
        gld16(Ag + (long)r * 64 * lda + k0 + h * 32, As + h * BM * 32 + r * 2048 + wave * 512);
#pragma unroll
      for (int r = 0; r < BR; r++)
        gld16(Bg + (long)r * 64 * ldb + k0 + h * 32, Bs + h * BN * 32 + r * 2048 + wave * 512);
    }
    __syncthreads();
#pragma unroll
    for (int h = 0; h < 2; h++) {
      s8_t af[FI], bfr[FJ];
#pragma unroll
      for (int t = 0; t < FI; t++)
        af[t] = *(const s8_t*)&As[h * BM * 32 + (wm + t * 16 + l16) * 32 + quad * 8];
#pragma unroll
      for (int t = 0; t < FJ; t++)
        bfr[t] = *(const s8_t*)&Bs[h * BN * 32 + (wn + t * 16 + l16) * 32 + quad * 8];
#pragma unroll
      for (int ti = 0; ti < FI; ti++)
#pragma unroll
        for (int tj = 0; tj < FJ; tj++)
          acc[ti][tj] = mfma16(af[ti], bfr[tj], acc[ti][tj]);
    }
    __syncthreads();
  }

#pragma unroll
  for (int ti = 0; ti < FI; ti++) {
#pragma unroll
    for (int tj = 0; tj < FJ; tj++) {
      const int n = bn + wn + tj * 16 + l16;
      const float bval = biasp ? biasp[n] : 0.f;
#pragma unroll
      for (int r = 0; r < 4; r++) {
        const int m = bm + wm + ti * 16 + quad * 4 + r;
        float vv = acc[ti][tj][r] + bval;
        if (RELU) vv = fmaxf(vv, 0.f);
        if (OUT_BF16) ((short*)Cv)[(long)m * ldc + n] = f2bf(vv);
        else          ((float*)Cv)[(long)m * ldc + n] = vv;
      }
    }
  }
}

// ---------------------------------------------------------------------------
// Attention with fused rel-pos, KT=64, FULL-ROW chunks (one block per q-tile).
// grid (B*H=32, 32):
//  y in [0,16): q-tile itile = 15-y (heavy first); iterates j0=0..itile*64,
//     online softmax across the whole row, DIRECT write (rows i>=fnp).
//  y in [16,32): pad-fallback q-tile (itile = y-16): rows i<fnp[b] are fully
//     masked -> unmasked attention over all 1024 keys; early-exits when
//     fnp[b] <= itile*64.
// Iteration body identical to the verified R11/R12 kernel.
// ---------------------------------------------------------------------------
__global__ __launch_bounds__(256) void attn_main(
    const short* __restrict__ qkv, const short* __restrict__ Eb,
    const int* __restrict__ xids, const int* __restrict__ fnp,
    short* __restrict__ outb) {
  __shared__ short Ks2[2][8][64][8];  // [buf][dim-group][key][8 dims]
  __shared__ short Vt[64][72];        // [dim][key]
  __shared__ short Gs[4][16][88];     // per wave: G band (cols 0..79) then P
  __shared__ short knegs[1024];       // bf16 pad-mask bias per key

  const int bh = blockIdx.x, b = bh >> 4, hh = bh & 15;
  const int yy = blockIdx.y;
  const bool fbp = (yy >= 16);
  const int itile = fbp ? (yy - 16) : (15 - yy);
  const int fb = fnp[b];
  const int i0g = itile * 64;
  if (fbp && fb <= i0g) return;

  const int tid = threadIdx.x;
  const int wave = tid >> 6, lane = tid & 63, quad = lane >> 4, l16 = lane & 15;
  const int i0 = i0g + wave * 16;

  // pad-mask table, once per block
  {
    const short neg = f2bf(-1e9f);
#pragma unroll
    for (int t = 0; t < 4; t++) {
      const int idx = t * 256 + tid;
      knegs[idx] = (xids[b * 1024 + idx] == 0) ? neg : (short)0;
    }
  }

  s8_t aq[2];
  {
    const short* qp = qkv + ((long)(b * 1024 + i0 + l16)) * 3072 + hh * 64 + quad * 8;
    aq[0] = *(const s8_t*)qp;
    aq[1] = *(const s8_t*)(qp + 32);
  }

  f4v o[4];
#pragma unroll
  for (int nt = 0; nt < 4; nt++) { f4v zz = {0.f, 0.f, 0.f, 0.f}; o[nt] = zz; }
  float m_run[4] = {-INFINITY, -INFINITY, -INFINITY, -INFINITY};
  float l_run[4] = {0.f, 0.f, 0.f, 0.f};

  const short* kbase = qkv + (long)b * 1024 * 3072 + 1024 + hh * 64 + wave * 8;
  const short* vbase = qkv + (long)b * 1024 * 3072 + 2048 + hh * 64 + wave * 16;
  short* gs = &Gs[wave][0][0];

  const int jEnd = fbp ? 1024 : (i0g + 64);

  // prologue: stage first chunk into buffer 0
  s8_t vr0, vr1;
  {
    const long k1 = min(0 + lane, 1023);
    gld16(kbase + k1 * 3072, &Ks2[0][wave][0][0]);
    gld16(kbase + k1 * 3072 + 32, &Ks2[0][wave + 4][0][0]);
    const short* vrow = vbase + k1 * 3072;
    vr0 = *(const s8_t*)(vrow);
    vr1 = *(const s8_t*)(vrow + 8);
#pragma unroll
    for (int t = 0; t < 8; t++) {
      Vt[wave * 16 + t][lane] = vr0[t];
      Vt[wave * 16 + 8 + t][lane] = vr1[t];
    }
  }

  int pb = 0;
  for (int j0 = 0; j0 < jEnd; j0 += 64) {
    const bool hasNext = (j0 + 64 < jEnd);
    __syncthreads();   // A: Ks2[pb], Vt, knegs visible to all waves

    // ---- fused rel-pos band: G[row][col'] = q_(i0+row) . E_(mW+col') ----
    {
      const int mW = 1008 - i0g - wave * 16 + j0;
#pragma unroll
      for (int t = 0; t < 5; t++) {
        const int m = min(mW + t * 16 + l16, 1023);
        const short* ep = Eb + m * 64 + quad * 8;
        const s8_t eb0 = *(const s8_t*)ep;
        const s8_t eb1 = *(const s8_t*)(ep + 32);
        f4v g = {0.f, 0.f, 0.f, 0.f};
        g = mfma16(aq[0], eb0, g);
        g = mfma16(aq[1], eb1, g);
#pragma unroll
        for (int r = 0; r < 4; r++)
          gs[(quad * 4 + r) * 88 + t * 16 + l16] = f2bf(g[r]);
      }
    }

    // ---- prefetch next chunk: K -> Ks2[pb^1] (async), V -> regs ----
    if (hasNext) {
      const long k1 = min(j0 + 64 + lane, 1023);
      gld16(kbase + k1 * 3072, &Ks2[pb ^ 1][wave][0][0]);
      gld16(kbase + k1 * 3072 + 32, &Ks2[pb ^ 1][wave + 4][0][0]);
      const short* vrow = vbase + k1 * 3072;
      vr0 = *(const s8_t*)(vrow);
      vr1 = *(const s8_t*)(vrow + 8);
    }

    // ---- scores 16x64: (qk + srel)*scale + mask ----
    float p[4][4];
    const int irow = i0 + quad * 4;
#pragma unroll
    for (int jt = 0; jt < 4; jt++) {
      const s8_t k0f = *(const s8_t*)&Ks2[pb][quad][jt * 16 + l16][0];
      const s8_t k1f = *(const s8_t*)&Ks2[pb][4 + quad][jt * 16 + l16][0];
      f4v zz = {0.f, 0.f, 0.f, 0.f};
      zz = mfma16(aq[0], k0f, zz);
      zz = mfma16(aq[1], k1f, zz);
      const int j = j0 + jt * 16 + l16;
      const float kn = bf2f(knegs[j]);
#pragma unroll
      for (int r = 0; r < 4; r++) {
        const int rr = quad * 4 + r;
        const float smv = bf2f(gs[rr * 87 + 15 + jt * 16 + l16]);
        const bool causal = (j <= irow + r);
        const float srel = causal ? smv : 0.f;
        const float kk = fbp ? 0.f : (causal ? kn : -1e9f);
        p[jt][r] = (zz[r] + srel) * 0.125f + kk;
      }
    }

    // ---- online softmax ----
    float alpha[4];
#pragma unroll
    for (int r = 0; r < 4; r++) {
      float mx = p[0][r];
#pragma unroll
      for (int jt = 1; jt < 4; jt++) mx = fmaxf(mx, p[jt][r]);
      mx = fmaxf(mx, __shfl_xor(mx, 1));
      mx = fmaxf(mx, __shfl_xor(mx, 2));
      mx = fmaxf(mx, __shfl_xor(mx, 4));
      mx = fmaxf(mx, __shfl_xor(mx, 8));
      const float mnew = fmaxf(m_run[r], mx);
      alpha[r] = __expf(m_run[r] - mnew);
      float ps = 0.f;
#pragma unroll
      for (int jt = 0; jt < 4; jt++) {
        p[jt][r] = __expf(p[jt][r] - mnew);
        ps += p[jt][r];
      }
      ps += __shfl_xor(ps, 1);
      ps += __shfl_xor(ps, 2);
      ps += __shfl_xor(ps, 4);
      ps += __shfl_xor(ps, 8);
      l_run[r] = l_run[r] * alpha[r] + ps;
      m_run[r] = mnew;
    }

    // ---- P -> LDS (A-layout, overwrites G cols 0..63), rescale O ----
#pragma unroll
    for (int jt = 0; jt < 4; jt++)
#pragma unroll
      for (int r = 0; r < 4; r++)
        gs[(quad * 4 + r) * 88 + jt * 16 + l16] = f2bf(p[jt][r]);
#pragma unroll
    for (int nt = 0; nt < 4; nt++)
#pragma unroll
      for (int r = 0; r < 4; r++)
        o[nt][r] *= alpha[r];

    // ---- O += P @ V (K=64) ----
#pragma unroll
    for (int ks4 = 0; ks4 < 2; ks4++) {
      const s8_t ap = *(const s8_t*)&gs[l16 * 88 + ks4 * 32 + quad * 8];
#pragma unroll
      for (int nt = 0; nt < 4; nt++) {
        const s8_t vf = *(const s8_t*)&Vt[nt * 16 + l16][ks4 * 32 + quad * 8];
        o[nt] = mfma16(ap, vf, o[nt]);
      }
    }

    __syncthreads();   // B: Vt reads done; prefetched K drained
    if (hasNext) {
#pragma unroll
      for (int t = 0; t < 8; t++) {
        Vt[wave * 16 + t][lane] = vr0[t];
        Vt[wave * 16 + 8 + t][lane] = vr1[t];
      }
    }
    pb ^= 1;
  }

  // ---- epilogue: direct write ----
  if (fbp) {
#pragma unroll
    for (int nt = 0; nt < 4; nt++)
#pragma unroll
      for (int r = 0; r < 4; r++) {
        const int i = i0 + quad * 4 + r;
        if (i < fb)
          outb[((long)(b * 1024 + i)) * 1024 + hh * 64 + nt * 16 + l16] =
              f2bf(o[nt][r] / l_run[r]);
      }
  } else {
#pragma unroll
    for (int nt = 0; nt < 4; nt++)
#pragma unroll
      for (int r = 0; r < 4; r++) {
        const int i = i0 + quad * 4 + r;
        if (i >= fb)
          outb[((long)(b * 1024 + i)) * 1024 + hh * 64 + nt * 16 + l16] =
              f2bf(o[nt][r] / l_run[r]);
      }
  }
}

// ---------------------------------------------------------------------------
extern "C" void kernel_launch(void* const* d_in, const int* in_sizes, int n_in,
                              void* d_out, int out_size, void* d_ws, size_t ws_size,
                              hipStream_t stream) {
  const int*   x   = (const int*)d_in[0];
  const float* emb = (const float*)d_in[1];
  const float* Wq  = (const float*)d_in[2];
  const float* bq  = (const float*)d_in[3];
  const float* Wk  = (const float*)d_in[4];
  const float* bk  = (const float*)d_in[5];
  const float* Wv  = (const float*)d_in[6];
  const float* bv  = (const float*)d_in[7];
  const float* Wo  = (const float*)d_in[8];
  const float* bo  = (const float*)d_in[9];
  const float* W1  = (const float*)d_in[10];
  const float* b1  = (const float*)d_in[11];
  const float* W2  = (const float*)d_in[12];
  const float* b2  = (const float*)d_in[13];
  const float* g1  = (const float*)d_in[14];
  const float* be1 = (const float*)d_in[15];
  const float* g2  = (const float*)d_in[16];
  const float* be2 = (const float*)d_in[17];
  const float* E   = (const float*)d_in[18];
  const float* Wf  = (const float*)d_in[19];
  const float* bfv = (const float*)d_in[20];

  char* p = (char*)d_ws;
  auto alloc = [&](size_t bytes) {
    char* r = p;
    p += (bytes + 255) & ~(size_t)255;
    return r;
  };
  short* h    = (short*)alloc(2048ull * 1024 * 2);
  short* qkv  = (short*)alloc(2048ull * 3072 * 2);
  short* attn = (short*)alloc(2048ull * 1024 * 2);
  short* tmp  = (short*)alloc(2048ull * 1024 * 2);
  short* mid  = (short*)alloc(2048ull * 512 * 2);
  short* qkvT = (short*)alloc(6ull * 3072 * 1024 * 2);
  short* WoT  = (short*)alloc(6ull * 1024 * 1024 * 2);
  short* W1T  = (short*)alloc(6ull * 512 * 1024 * 2);
  short* W2T  = (short*)alloc(6ull * 1024 * 512 * 2);
  short* WfT  = (short*)alloc(256ull * 1024 * 2);
  short* Ebf  = (short*)alloc(6ull * 1024 * 64 * 2);
  float* qkvB = (float*)alloc(6ull * 3072 * 4);
  int*   fnp  = (int*)alloc(256);

  prep_weights<<<3872, 256, 0, stream>>>(
      Wq, Wk, Wv, Wo, W1, W2, Wf, qkvT, WoT, W1T, W2T, WfT);
  prep_misc<<<2506, 256, 0, stream>>>(x, emb, E, bq, bk, bv, h, Ebf, qkvB, fnp);

  for (int l = 0; l < 6; l++) {
    const long wOff = (long)l * 1024 * 1024;
    const long w12Off = (long)l * 512 * 1024;
    gemm_lds<128, 128, 2, 2, 1, 0><<<dim3(24, 16), 256, 0, stream>>>(
        h, qkvT + (long)l * 3072 * 1024, qkv, qkvB + l * 3072, 1024, 1024, 1024, 3072);
    attn_main<<<dim3(32, 32), 256, 0, stream>>>(
        qkv, Ebf + (long)l * 1024 * 64, x, fnp, attn);
    gemm_lds<64, 64, 2, 2, 1, 0><<<dim3(16, 32), 256, 0, stream>>>(
        attn, WoT + wOff, tmp, bo + l * 1024, 1024, 1024, 1024, 1024);
    ln_kernel<<<512, 256, 0, stream>>>(tmp, tmp, g1 + l * 1024, be1 + l * 1024);
    gemm_lds<64, 64, 2, 2, 1, 1><<<dim3(8, 32), 256, 0, stream>>>(
        tmp, W1T + w12Off, mid, b1 + l * 512, 1024, 1024, 1024, 512);
    gemm_lds<64, 64, 2, 2, 1, 0><<<dim3(16, 32), 256, 0, stream>>>(
        mid, W2T + w12Off, h, b2 + l * 1024, 512, 512, 512, 1024);
    ln_kernel<<<512, 256, 0, stream>>>(h, h, g2 + l * 1024, be2 + l * 1024);
  }
  gemm_lds<64, 64, 2, 2, 0, 0><<<dim3(4, 32), 256, 0, stream>>>(
      h, WfT, (float*)d_out, bfv, 1024, 1024, 1024, 256);
}

// Round 10
// 885.279 us; speedup vs baseline: 1.0745x; 1.0745x over previous
//
#include <hip/hip_runtime.h>
#include <hip/hip_bf16.h>

// ---------------------------------------------------------------------------
// ArrowTransformer forward: B=2, S=1024, D=1024, H=16, HD=64, L=6, V=256
// Round 14 (base = R12/901us):
//  * attn_main/attn_combine: reverted VERBATIM to R12 (512-key chunks,
//    PO/PM/PL partials). R13's 1024-key full-row variant regressed
//    (occupancy 23->12%, attn 53->62.6us) -> 512 is the chunk-size knee.
//  * qkv GEMM: 64x128 tiles, grid (24,32)=768 blocks = 3 blocks/CU
//    (was 128x128, 384 blocks = 1.5/CU) -- occupancy lever on the one
//    remaining low-concurrency kernel.
//  * prep_weights 64x128, ln one-wave, gemm BK=64: unchanged from R12.
// ---------------------------------------------------------------------------

typedef __attribute__((ext_vector_type(8))) short  s8_t;
typedef __attribute__((ext_vector_type(4))) short  s4_t;
typedef __attribute__((ext_vector_type(8))) __bf16 bf8_t;
typedef __attribute__((ext_vector_type(4))) float  f4v;

static __device__ __forceinline__ short f2bf(float f) {
  union { float f; unsigned u; } a; a.f = f;
  unsigned u = a.u;
  u += 0x7fffu + ((u >> 16) & 1u);
  return (short)(u >> 16);
}
static __device__ __forceinline__ float bf2f(short s) {
  union { float f; unsigned u; } a;
  a.u = ((unsigned)(unsigned short)s) << 16;
  return a.f;
}
static __device__ __forceinline__ f4v mfma16(s8_t a, s8_t b, f4v c) {
  return __builtin_amdgcn_mfma_f32_16x16x32_bf16(
      __builtin_bit_cast(bf8_t, a), __builtin_bit_cast(bf8_t, b), c, 0, 0, 0);
}
static __device__ __forceinline__ void gld16(const short* g, short* l) {
  __builtin_amdgcn_global_load_lds(
      (const __attribute__((address_space(1))) void*)g,
      (__attribute__((address_space(3))) void*)l, 16, 0, 0);
}

// 512-key chunks: nc(itile) = (itile>=8) ? 2 : 1. Heavy blocks first.
static __device__ const int IT_TAB[24] = {
  15,15,14,13,12,11,10,9,8,7, 14,6, 13,5, 12,4, 11,3, 10,2, 9,1, 8,0};
static __device__ const int CW_TAB[24] = {
   0, 1, 0, 0, 0, 0, 0,0,0,0,  1,0,  1,0,  1,0,  1,0,  1,0, 1,0, 1,0};

// ---------------------------------------------------------------------------
// Unified weight prep: all transposes (f32 -> bf16, [N][K] layout).
// 64x128 input tiles, 256 threads, grid 3872.
// ---------------------------------------------------------------------------
__global__ __launch_bounds__(256) void prep_weights(
    const float* __restrict__ Wq, const float* __restrict__ Wk,
    const float* __restrict__ Wv, const float* __restrict__ Wo,
    const float* __restrict__ W1, const float* __restrict__ W2,
    const float* __restrict__ Wf,
    short* __restrict__ qkvT, short* __restrict__ WoT, short* __restrict__ W1T,
    short* __restrict__ W2T, short* __restrict__ WfT) {
  __shared__ float tile[64][133];
  int z = blockIdx.x;
  const float* in; short* out; int R, C; long outBS; int rowOff = 0;
  if (z < 2304) {
    R = 1024; C = 1024; outBS = (long)3072 * 1024; out = qkvT;
    if (z < 768)       { in = Wq; }
    else if (z < 1536) { in = Wk; rowOff = 1024; z -= 768; }
    else               { in = Wv; rowOff = 2048; z -= 1536; }
  } else if (z < 3072) { in = Wo; out = WoT; R = 1024; C = 1024; outBS = (long)1024 * 1024; z -= 2304; }
  else if (z < 3456)   { in = W1; out = W1T; R = 1024; C = 512;  outBS = (long)512 * 1024;  z -= 3072; }
  else if (z < 3840)   { in = W2; out = W2T; R = 512;  C = 1024; outBS = (long)1024 * 512;  z -= 3456; }
  else                 { in = Wf; out = WfT; R = 1024; C = 256;  outBS = 0;                 z -= 3840; }
  const int nx = C >> 7, ny = R >> 6;
  const int per = nx * ny;
  const int l = z / per, rem = z % per;
  const int cx = rem % nx, cy = rem / nx;
  in += (long)l * R * C;
  out += (long)l * outBS + (long)rowOff * R;
  const int c0 = cx * 128, r0 = cy * 64;
  const int tid = threadIdx.x;

  const int lr = tid >> 4, lc4 = tid & 15;
#pragma unroll
  for (int p = 0; p < 4; p++) {
    const int row = p * 16 + lr;
#pragma unroll
    for (int h = 0; h < 2; h++) {
      const float4 v = *(const float4*)(in + (long)(r0 + row) * C + c0 + h * 64 + lc4 * 4);
      tile[row][h * 64 + lc4 * 4 + 0] = v.x;
      tile[row][h * 64 + lc4 * 4 + 1] = v.y;
      tile[row][h * 64 + lc4 * 4 + 2] = v.z;
      tile[row][h * 64 + lc4 * 4 + 3] = v.w;
    }
  }
  __syncthreads();
  const int seg = tid & 7;
#pragma unroll
  for (int q = 0; q < 4; q++) {
    const int oc = q * 32 + (tid >> 3);   // output row = source column (0..127)
    s8_t o;
#pragma unroll
    for (int j = 0; j < 8; j++) o[j] = f2bf(tile[seg * 8 + j][oc]);
    *(s8_t*)(out + (long)(c0 + oc) * R + r0 + seg * 8) = o;
  }
}

// ---------------------------------------------------------------------------
// Misc prep: embed+PE (blocks 0..2047), E->bf16 (2048..2431),
// qkv bias concat (2432..2503), fnp (2504..2505). 256 threads.
// ---------------------------------------------------------------------------
__global__ __launch_bounds__(256) void prep_misc(
    const int* __restrict__ x, const float* __restrict__ emb,
    const float* __restrict__ E,
    const float* __restrict__ bq, const float* __restrict__ bk,
    const float* __restrict__ bv,
    short* __restrict__ h, short* __restrict__ Ebf,
    float* __restrict__ qkvB, int* __restrict__ fnp) {
  const int z = blockIdx.x;
  const int tid = threadIdx.x;
  if (z < 2048) {
    const int s = z & 1023;
    const int xv = x[z];
    const int c = tid << 2;
    const float4 e = *(const float4*)(emb + (long)xv * 1024 + c);
    const float ev[4] = {e.x, e.y, e.z, e.w};
    s4_t o;
#pragma unroll
    for (int i = 0; i < 4; i++) {
      const int d = c + i;
      const float par = (float)(d & 1);
      const float rate = expf(-9.210340371976184f * (float)d / 1024.0f) *
                         expf(9.210340371976184f * par / 1024.0f);
      const float pe = sinf((float)s * rate + 1.5707963267948966f * par);
      o[i] = f2bf(ev[i] * 32.0f + pe);
    }
    *(s4_t*)(h + (long)z * 1024 + c) = o;
  } else if (z < 2432) {
    const long i = ((long)(z - 2048) * 256 + tid) * 4;
    const float4 t = *(const float4*)(E + i);
    s4_t o = {f2bf(t.x), f2bf(t.y), f2bf(t.z), f2bf(t.w)};
    *(s4_t*)(Ebf + i) = o;
  } else if (z < 2504) {
    const int idx = (z - 2432) * 256 + tid;
    const int l = idx / 3072, n = idx % 3072;
    float v = (n < 1024) ? bq[l * 1024 + n]
            : (n < 2048) ? bk[l * 1024 + n - 1024]
                         : bv[l * 1024 + n - 2048];
    qkvB[idx] = v;
  } else {
    if (tid < 64) {
      const int b = z - 2504;
      int first = 1024;
      for (int j0 = 0; j0 < 1024; j0 += 64) {
        unsigned long long m = __ballot(x[b * 1024 + j0 + tid] != 0);
        if (m) { first = j0 + __ffsll(m) - 1; break; }
      }
      if (tid == 0) fnp[b] = first;
    }
  }
}

// ---------------------------------------------------------------------------
// LayerNorm over D=1024, bf16 in/out. ONE WAVE per row (no barriers/LDS).
// grid 512 x 256 threads (4 rows/block). In-place safe.
// ---------------------------------------------------------------------------
__global__ __launch_bounds__(256) void ln_kernel(const short* __restrict__ in,
                                                 short* __restrict__ out,
                                                 const float* __restrict__ g,
                                                 const float* __restrict__ be) {
  const int tid = threadIdx.x;
  const int row = blockIdx.x * 4 + (tid >> 6);
  const int lane = tid & 63;
  const int c = lane * 16;
  const short* ip = in + (long)row * 1024 + c;
  s4_t xv[4];
#pragma unroll
  for (int t = 0; t < 4; t++) xv[t] = *(const s4_t*)(ip + t * 4);
  float xs[16];
  float s = 0.f;
#pragma unroll
  for (int t = 0; t < 4; t++)
#pragma unroll
    for (int i = 0; i < 4; i++) {
      xs[t * 4 + i] = bf2f(xv[t][i]);
      s += xs[t * 4 + i];
    }
#pragma unroll
  for (int off = 1; off < 64; off <<= 1) s += __shfl_xor(s, off);
  const float mu = s * (1.0f / 1024.0f);
  float q = 0.f;
#pragma unroll
  for (int t = 0; t < 16; t++) {
    xs[t] -= mu;
    q += xs[t] * xs[t];
  }
#pragma unroll
  for (int off = 1; off < 64; off <<= 1) q += __shfl_xor(q, off);
  const float var = q * (1.0f / 1024.0f);
  const float rs = rsqrtf(var + 1e-6f);
  short* op = out + (long)row * 1024 + c;
#pragma unroll
  for (int t = 0; t < 4; t++) {
    const float4 gv = *(const float4*)(g + c + t * 4);
    const float4 bv = *(const float4*)(be + c + t * 4);
    s4_t o = {f2bf(xs[t * 4 + 0] * rs * gv.x + bv.x),
              f2bf(xs[t * 4 + 1] * rs * gv.y + bv.y),
              f2bf(xs[t * 4 + 2] * rs * gv.z + bv.z),
              f2bf(xs[t * 4 + 3] * rs * gv.w + bv.w)};
    *(s4_t*)(op + t * 4) = o;
  }
}

// ---------------------------------------------------------------------------
// Generic MFMA GEMM: C[m][n] = sum_k A[m][k]*BT[n][k] (+bias) (+relu)
// BK=64 via two half-tiles per barrier window (proven R12 structure).
// ---------------------------------------------------------------------------
template <int BM, int BN, int WR, int WC, int OUT_BF16, int RELU>
__global__ __launch_bounds__(256) void gemm_lds(
    const short* __restrict__ A, const short* __restrict__ BT,
    void* __restrict__ Cv, const float* __restrict__ biasp,
    int K, int lda, int ldb, int ldc) {
  constexpr int AR = BM / 64, BR = BN / 64;
  constexpr int FI = BM / WR / 16, FJ = BN / WC / 16;
  __shared__ short As[2 * BM * 32];
  __shared__ short Bs[2 * BN * 32];
  const int bm = blockIdx.y * BM, bn = blockIdx.x * BN;
  const int tid = threadIdx.x;
  const int wave = tid >> 6, lane = tid & 63;
  const int quad = lane >> 4, l16 = lane & 15;
  const int wr = wave / WC, wc = wave % WC;
  const int wm = wr * (BM / WR), wn = wc * (BN / WC);

  const short* Ag = A + (long)(bm + wave * 16 + (lane >> 2)) * lda + ((lane & 3) << 3);
  const short* Bg = BT + (long)(bn + wave * 16 + (lane >> 2)) * ldb + ((lane & 3) << 3);

  f4v acc[FI][FJ];
#pragma unroll
  for (int i = 0; i < FI; i++)
#pragma unroll
    for (int j = 0; j < FJ; j++) {
      f4v zz = {0.f, 0.f, 0.f, 0.f};
      acc[i][j] = zz;
    }

  for (int k0 = 0; k0 < K; k0 += 64) {
#pragma unroll
    for (int h = 0; h < 2; h++) {
#pragma unroll
      for (int r = 0; r < AR; r++)
        gld16(Ag + (long)r * 64 * lda + k0 + h * 32, As + h * BM * 32 + r * 2048 + wave * 512);
#pragma unroll
      for (int r = 0; r < BR; r++)
        gld16(Bg + (long)r * 64 * ldb + k0 + h * 32, Bs + h * BN * 32 + r * 2048 + wave * 512);
    }
    __syncthreads();
#pragma unroll
    for (int h = 0; h < 2; h++) {
      s8_t af[FI], bfr[FJ];
#pragma unroll
      for (int t = 0; t < FI; t++)
        af[t] = *(const s8_t*)&As[h * BM * 32 + (wm + t * 16 + l16) * 32 + quad * 8];
#pragma unroll
      for (int t = 0; t < FJ; t++)
        bfr[t] = *(const s8_t*)&Bs[h * BN * 32 + (wn + t * 16 + l16) * 32 + quad * 8];
#pragma unroll
      for (int ti = 0; ti < FI; ti++)
#pragma unroll
        for (int tj = 0; tj < FJ; tj++)
          acc[ti][tj] = mfma16(af[ti], bfr[tj], acc[ti][tj]);
    }
    __syncthreads();
  }

#pragma unroll
  for (int ti = 0; ti < FI; ti++) {
#pragma unroll
    for (int tj = 0; tj < FJ; tj++) {
      const int n = bn + wn + tj * 16 + l16;
      const float bval = biasp ? biasp[n] : 0.f;
#pragma unroll
      for (int r = 0; r < 4; r++) {
        const int m = bm + wm + ti * 16 + quad * 4 + r;
        float vv = acc[ti][tj][r] + bval;
        if (RELU) vv = fmaxf(vv, 0.f);
        if (OUT_BF16) ((short*)Cv)[(long)m * ldc + n] = f2bf(vv);
        else          ((float*)Cv)[(long)m * ldc + n] = vv;
      }
    }
  }
}

// ---------------------------------------------------------------------------
// Attention with fused rel-pos, KT=64, 512-key chunks, two-barrier pipeline.
// VERBATIM from Round 12 (passing, 901us).
// ---------------------------------------------------------------------------
__global__ __launch_bounds__(256) void attn_main(
    const short* __restrict__ qkv, const short* __restrict__ Eb,
    const int* __restrict__ xids, const int* __restrict__ fnp,
    float* __restrict__ PO, float* __restrict__ PM, float* __restrict__ PL,
    short* __restrict__ outb) {
  __shared__ short Ks2[2][8][64][8];  // [buf][dim-group][key][8 dims]
  __shared__ short Vt[64][72];        // [dim][key]
  __shared__ short Gs[4][16][88];     // per wave: G band (cols 0..79) then P
  __shared__ short knegs[1024];       // bf16 pad-mask bias per key

  const int bh = blockIdx.x, b = bh >> 4, hh = bh & 15;
  const int yy = blockIdx.y;
  const bool fbp = (yy >= 24);
  const int itile = fbp ? (yy - 24) : IT_TAB[yy];
  const int cw = fbp ? 0 : CW_TAB[yy];
  const int fb = fnp[b];
  const int i0g = itile * 64;
  if (fbp && fb <= i0g) return;

  const int tid = threadIdx.x;
  const int wave = tid >> 6, lane = tid & 63, quad = lane >> 4, l16 = lane & 15;
  const int i0 = i0g + wave * 16;

  // pad-mask table, once per block
  {
    const short neg = f2bf(-1e9f);
#pragma unroll
    for (int t = 0; t < 4; t++) {
      const int idx = t * 256 + tid;
      knegs[idx] = (xids[b * 1024 + idx] == 0) ? neg : (short)0;
    }
  }

  s8_t aq[2];
  {
    const short* qp = qkv + ((long)(b * 1024 + i0 + l16)) * 3072 + hh * 64 + quad * 8;
    aq[0] = *(const s8_t*)qp;
    aq[1] = *(const s8_t*)(qp + 32);
  }

  f4v o[4];
#pragma unroll
  for (int nt = 0; nt < 4; nt++) { f4v zz = {0.f, 0.f, 0.f, 0.f}; o[nt] = zz; }
  float m_run[4] = {-INFINITY, -INFINITY, -INFINITY, -INFINITY};
  float l_run[4] = {0.f, 0.f, 0.f, 0.f};

  const short* kbase = qkv + (long)b * 1024 * 3072 + 1024 + hh * 64 + wave * 8;
  const short* vbase = qkv + (long)b * 1024 * 3072 + 2048 + hh * 64 + wave * 16;
  short* gs = &Gs[wave][0][0];

  const int jBeg = fbp ? 0 : cw * 512;
  const int jEnd = fbp ? 1024 : min(cw * 512 + 512, i0g + 64);

  // prologue: stage first chunk into buffer 0
  s8_t vr0, vr1;
  {
    const long k1 = min(jBeg + lane, 1023);
    gld16(kbase + k1 * 3072, &Ks2[0][wave][0][0]);
    gld16(kbase + k1 * 3072 + 32, &Ks2[0][wave + 4][0][0]);
    const short* vrow = vbase + k1 * 3072;
    vr0 = *(const s8_t*)(vrow);
    vr1 = *(const s8_t*)(vrow + 8);
#pragma unroll
    for (int t = 0; t < 8; t++) {
      Vt[wave * 16 + t][lane] = vr0[t];
      Vt[wave * 16 + 8 + t][lane] = vr1[t];
    }
  }

  int pb = 0;
  for (int j0 = jBeg; j0 < jEnd; j0 += 64) {
    const bool hasNext = (j0 + 64 < jEnd);
    __syncthreads();   // A: Ks2[pb], Vt, knegs visible to all waves

    // ---- fused rel-pos band: G[row][col'] = q_(i0+row) . E_(mW+col') ----
    {
      const int mW = 1008 - i0g - wave * 16 + j0;
#pragma unroll
      for (int t = 0; t < 5; t++) {
        const int m = min(mW + t * 16 + l16, 1023);
        const short* ep = Eb + m * 64 + quad * 8;
        const s8_t eb0 = *(const s8_t*)ep;
        const s8_t eb1 = *(const s8_t*)(ep + 32);
        f4v g = {0.f, 0.f, 0.f, 0.f};
        g = mfma16(aq[0], eb0, g);
        g = mfma16(aq[1], eb1, g);
#pragma unroll
        for (int r = 0; r < 4; r++)
          gs[(quad * 4 + r) * 88 + t * 16 + l16] = f2bf(g[r]);
      }
    }

    // ---- prefetch next chunk: K -> Ks2[pb^1] (async), V -> regs ----
    if (hasNext) {
      const long k1 = min(j0 + 64 + lane, 1023);
      gld16(kbase + k1 * 3072, &Ks2[pb ^ 1][wave][0][0]);
      gld16(kbase + k1 * 3072 + 32, &Ks2[pb ^ 1][wave + 4][0][0]);
      const short* vrow = vbase + k1 * 3072;
      vr0 = *(const s8_t*)(vrow);
      vr1 = *(const s8_t*)(vrow + 8);
    }

    // ---- scores 16x64: (qk + srel)*scale + mask ----
    float p[4][4];
    const int irow = i0 + quad * 4;
#pragma unroll
    for (int jt = 0; jt < 4; jt++) {
      const s8_t k0f = *(const s8_t*)&Ks2[pb][quad][jt * 16 + l16][0];
      const s8_t k1f = *(const s8_t*)&Ks2[pb][4 + quad][jt * 16 + l16][0];
      f4v zz = {0.f, 0.f, 0.f, 0.f};
      zz = mfma16(aq[0], k0f, zz);
      zz = mfma16(aq[1], k1f, zz);
      const int j = j0 + jt * 16 + l16;
      const float kn = bf2f(knegs[j]);
#pragma unroll
      for (int r = 0; r < 4; r++) {
        const int rr = quad * 4 + r;
        const float smv = bf2f(gs[rr * 87 + 15 + jt * 16 + l16]);
        const bool causal = (j <= irow + r);
        const float srel = causal ? smv : 0.f;
        const float kk = fbp ? 0.f : (causal ? kn : -1e9f);
        p[jt][r] = (zz[r] + srel) * 0.125f + kk;
      }
    }

    // ---- online softmax ----
    float alpha[4];
#pragma unroll
    for (int r = 0; r < 4; r++) {
      float mx = p[0][r];
#pragma unroll
      for (int jt = 1; jt < 4; jt++) mx = fmaxf(mx, p[jt][r]);
      mx = fmaxf(mx, __shfl_xor(mx, 1));
      mx = fmaxf(mx, __shfl_xor(mx, 2));
      mx = fmaxf(mx, __shfl_xor(mx, 4));
      mx = fmaxf(mx, __shfl_xor(mx, 8));
      const float mnew = fmaxf(m_run[r], mx);
      alpha[r] = __expf(m_run[r] - mnew);
      float ps = 0.f;
#pragma unroll
      for (int jt = 0; jt < 4; jt++) {
        p[jt][r] = __expf(p[jt][r] - mnew);
        ps += p[jt][r];
      }
      ps += __shfl_xor(ps, 1);
      ps += __shfl_xor(ps, 2);
      ps += __shfl_xor(ps, 4);
      ps += __shfl_xor(ps, 8);
      l_run[r] = l_run[r] * alpha[r] + ps;
      m_run[r] = mnew;
    }

    // ---- P -> LDS (A-layout, overwrites G cols 0..63), rescale O ----
#pragma unroll
    for (int jt = 0; jt < 4; jt++)
#pragma unroll
      for (int r = 0; r < 4; r++)
        gs[(quad * 4 + r) * 88 + jt * 16 + l16] = f2bf(p[jt][r]);
#pragma unroll
    for (int nt = 0; nt < 4; nt++)
#pragma unroll
      for (int r = 0; r < 4; r++)
        o[nt][r] *= alpha[r];

    // ---- O += P @ V (K=64) ----
#pragma unroll
    for (int ks4 = 0; ks4 < 2; ks4++) {
      const s8_t ap = *(const s8_t*)&gs[l16 * 88 + ks4 * 32 + quad * 8];
#pragma unroll
      for (int nt = 0; nt < 4; nt++) {
        const s8_t vf = *(const s8_t*)&Vt[nt * 16 + l16][ks4 * 32 + quad * 8];
        o[nt] = mfma16(ap, vf, o[nt]);
      }
    }

    __syncthreads();   // B: Vt reads done; prefetched K drained
    if (hasNext) {
#pragma unroll
      for (int t = 0; t < 8; t++) {
        Vt[wave * 16 + t][lane] = vr0[t];
        Vt[wave * 16 + 8 + t][lane] = vr1[t];
      }
    }
    pb ^= 1;
  }

  // ---- epilogue ----
  if (fbp) {
#pragma unroll
    for (int nt = 0; nt < 4; nt++)
#pragma unroll
      for (int r = 0; r < 4; r++) {
        const int i = i0 + quad * 4 + r;
        if (i < fb)
          outb[((long)(b * 1024 + i)) * 1024 + hh * 64 + nt * 16 + l16] =
              f2bf(o[nt][r] / l_run[r]);
      }
  } else if (itile < 8) {   // nc==1: single chunk -> direct write
#pragma unroll
    for (int nt = 0; nt < 4; nt++)
#pragma unroll
      for (int r = 0; r < 4; r++) {
        const int i = i0 + quad * 4 + r;
        if (i >= fb)
          outb[((long)(b * 1024 + i)) * 1024 + hh * 64 + nt * 16 + l16] =
              f2bf(o[nt][r] / l_run[r]);
      }
  } else {
    const long part = (long)(bh * 16 + itile) * 2 + cw;
    float* po = PO + part * 4096;
#pragma unroll
    for (int nt = 0; nt < 4; nt++)
#pragma unroll
      for (int r = 0; r < 4; r++) {
        const int row = wave * 16 + quad * 4 + r;
        po[row * 64 + nt * 16 + l16] = o[nt][r];
      }
    if (l16 == 0) {
#pragma unroll
      for (int r = 0; r < 4; r++) {
        const int row = wave * 16 + quad * 4 + r;
        PM[part * 64 + row] = m_run[r];
        PL[part * 64 + row] = l_run[r];
      }
    }
  }
}

// combine 2 partial chunks -> output for itile>=8. grid 256 (32 bh x 8).
__global__ __launch_bounds__(256) void attn_combine(
    const float* __restrict__ PO, const float* __restrict__ PM,
    const float* __restrict__ PL, const int* __restrict__ fnp,
    short* __restrict__ outb) {
  const int id = blockIdx.x;
  const int bh = id >> 3, itile = 8 + (id & 7);
  const int b = bh >> 4, hh = bh & 15;
  const int row = threadIdx.x >> 2, seg = (threadIdx.x & 3) << 4;
  const long base = (long)(bh * 16 + itile) * 2;
  const int i = itile * 64 + row;
  if (i < fnp[b]) return;   // fully-masked rows handled by fallback path

  const float m0 = PM[base * 64 + row];
  const float m1 = PM[(base + 1) * 64 + row];
  const float M = fmaxf(m0, m1);
  const float w0 = __expf(m0 - M), w1 = __expf(m1 - M);
  const float l = w0 * PL[base * 64 + row] + w1 * PL[(base + 1) * 64 + row];
  const float* po0 = PO + base * 4096 + row * 64 + seg;
  const float* po1 = PO + (base + 1) * 4096 + row * 64 + seg;
  const float inv = 1.0f / l;
  short* op = outb + ((long)(b * 1024 + i)) * 1024 + hh * 64 + seg;
#pragma unroll
  for (int t = 0; t < 4; t++) {
    const f4v v0 = *(const f4v*)(po0 + t * 4);
    const f4v v1 = *(const f4v*)(po1 + t * 4);
    s4_t o = {f2bf((w0 * v0[0] + w1 * v1[0]) * inv),
              f2bf((w0 * v0[1] + w1 * v1[1]) * inv),
              f2bf((w0 * v0[2] + w1 * v1[2]) * inv),
              f2bf((w0 * v0[3] + w1 * v1[3]) * inv)};
    *(s4_t*)(op + t * 4) = o;
  }
}

// ---------------------------------------------------------------------------
extern "C" void kernel_launch(void* const* d_in, const int* in_sizes, int n_in,
                              void* d_out, int out_size, void* d_ws, size_t ws_size,
                              hipStream_t stream) {
  const int*   x   = (const int*)d_in[0];
  const float* emb = (const float*)d_in[1];
  const float* Wq  = (const float*)d_in[2];
  const float* bq  = (const float*)d_in[3];
  const float* Wk  = (const float*)d_in[4];
  const float* bk  = (const float*)d_in[5];
  const float* Wv  = (const float*)d_in[6];
  const float* bv  = (const float*)d_in[7];
  const float* Wo  = (const float*)d_in[8];
  const float* bo  = (const float*)d_in[9];
  const float* W1  = (const float*)d_in[10];
  const float* b1  = (const float*)d_in[11];
  const float* W2  = (const float*)d_in[12];
  const float* b2  = (const float*)d_in[13];
  const float* g1  = (const float*)d_in[14];
  const float* be1 = (const float*)d_in[15];
  const float* g2  = (const float*)d_in[16];
  const float* be2 = (const float*)d_in[17];
  const float* E   = (const float*)d_in[18];
  const float* Wf  = (const float*)d_in[19];
  const float* bfv = (const float*)d_in[20];

  char* p = (char*)d_ws;
  auto alloc = [&](size_t bytes) {
    char* r = p;
    p += (bytes + 255) & ~(size_t)255;
    return r;
  };
  short* h    = (short*)alloc(2048ull * 1024 * 2);
  short* qkv  = (short*)alloc(2048ull * 3072 * 2);
  short* attn = (short*)alloc(2048ull * 1024 * 2);
  short* tmp  = (short*)alloc(2048ull * 1024 * 2);
  short* mid  = (short*)alloc(2048ull * 512 * 2);
  short* qkvT = (short*)alloc(6ull * 3072 * 1024 * 2);
  short* WoT  = (short*)alloc(6ull * 1024 * 1024 * 2);
  short* W1T  = (short*)alloc(6ull * 512 * 1024 * 2);
  short* W2T  = (short*)alloc(6ull * 1024 * 512 * 2);
  short* WfT  = (short*)alloc(256ull * 1024 * 2);
  short* Ebf  = (short*)alloc(6ull * 1024 * 64 * 2);
  float* qkvB = (float*)alloc(6ull * 3072 * 4);
  int*   fnp  = (int*)alloc(256);
  float* PO   = (float*)alloc(2048ull * 4096 * 4);
  float* PM   = (float*)alloc(2048ull * 64 * 4);
  float* PL   = (float*)alloc(2048ull * 64 * 4);

  prep_weights<<<3872, 256, 0, stream>>>(
      Wq, Wk, Wv, Wo, W1, W2, Wf, qkvT, WoT, W1T, W2T, WfT);
  prep_misc<<<2506, 256, 0, stream>>>(x, emb, E, bq, bk, bv, h, Ebf, qkvB, fnp);

  for (int l = 0; l < 6; l++) {
    const long wOff = (long)l * 1024 * 1024;
    const long w12Off = (long)l * 512 * 1024;
    gemm_lds<64, 128, 2, 2, 1, 0><<<dim3(24, 32), 256, 0, stream>>>(
        h, qkvT + (long)l * 3072 * 1024, qkv, qkvB + l * 3072, 1024, 1024, 1024, 3072);
    attn_main<<<dim3(32, 40), 256, 0, stream>>>(
        qkv, Ebf + (long)l * 1024 * 64, x, fnp, PO, PM, PL, attn);
    attn_combine<<<256, 256, 0, stream>>>(PO, PM, PL, fnp, attn);
    gemm_lds<64, 64, 2, 2, 1, 0><<<dim3(16, 32), 256, 0, stream>>>(
        attn, WoT + wOff, tmp, bo + l * 1024, 1024, 1024, 1024, 1024);
    ln_kernel<<<512, 256, 0, stream>>>(tmp, tmp, g1 + l * 1024, be1 + l * 1024);
    gemm_lds<64, 64, 2, 2, 1, 1><<<dim3(8, 32), 256, 0, stream>>>(
        tmp, W1T + w12Off, mid, b1 + l * 512, 1024, 1024, 1024, 512);
    gemm_lds<64, 64, 2, 2, 1, 0><<<dim3(16, 32), 256, 0, stream>>>(
        mid, W2T + w12Off, h, b2 + l * 1024, 512, 512, 512, 1024);
    ln_kernel<<<512, 256, 0, stream>>>(h, h, g2 + l * 1024, be2 + l * 1024);
  }
  gemm_lds<64, 64, 2, 2, 0, 0><<<dim3(4, 32), 256, 0, stream>>>(
      h, WfT, (float*)d_out, bfv, 1024, 1024, 1024, 256);
}